// Round 3
// baseline (254.270 us; speedup 1.0000x reference)
//
#include <hip/hip_runtime.h>

#define NV 40962
#define NK 9
#define CIN 32
#define COUT 32
#define NBS 4
#define VT 256                 // transpose v-tile
#define TP 260                 // transpose LDS row stride (dwords)
#define APAD 296               // Alds row stride (shorts), 288 used

typedef __attribute__((ext_vector_type(8))) short bf16x8;
typedef __attribute__((ext_vector_type(4))) float f32x4;

// round-to-nearest-even f32 -> bf16 pair packed in a dword (a=low, b=high)
__device__ __forceinline__ unsigned bf16pair(float a, float b) {
    unsigned ua = __float_as_uint(a), ub = __float_as_uint(b);
    ua = (ua + 0x7FFFu + ((ua >> 16) & 1u)) >> 16;
    ub = (ub + 0x7FFFu + ((ub >> 16) & 1u)) & 0xFFFF0000u;
    return (ua & 0xFFFFu) | ub;
}

// ---------------------------------------------------------------------------
// Kernel 1: x [128 rows=(b*32+c)][V] f32 -> xt_b[b][v][32ch] bf16.
// Block = (b, 256-v tile): reads are 1KB-contiguous per channel row,
// writes are 1KB-contiguous uint4 streams. LDS holds ch-PAIR dwords.
// ---------------------------------------------------------------------------
__global__ void __launch_bounds__(256) transpose_x_bf16(
    const float* __restrict__ x, unsigned* __restrict__ xtw)
{
    __shared__ unsigned T[16 * TP];          // 16 ch-pairs x 260 dwords = 16.6 KB
    const int b  = blockIdx.x & 3;
    const int v0 = (blockIdx.x >> 2) * VT;
    const int t  = threadIdx.x;
    const int w  = t >> 6;
    const int L  = t & 63;
    const bool full = (v0 + VT <= NV);

    #pragma unroll
    for (int i = 0; i < 4; ++i) {
        const int q = w + 4 * i;             // ch-pair 0..15 (ch 2q, 2q+1)
        const float* rowA = x + (size_t)(b * 32 + 2 * q) * NV;
        const float* rowB = rowA + NV;
        #pragma unroll
        for (int h = 0; h < 2; ++h) {
            const int vl = 128 * h + 2 * L;  // 0..254 (even)
            float2 a, c;
            if (full) {
                a = *(const float2*)(rowA + v0 + vl);
                c = *(const float2*)(rowB + v0 + vl);
            } else {
                const int v = v0 + vl;
                a.x = (v     < NV) ? rowA[v]     : 0.0f;
                a.y = (v + 1 < NV) ? rowA[v + 1] : 0.0f;
                c.x = (v     < NV) ? rowB[v]     : 0.0f;
                c.y = (v + 1 < NV) ? rowB[v + 1] : 0.0f;
            }
            uint2 d;
            d.x = bf16pair(a.x, c.x);        // (ch 2q, 2q+1) for v
            d.y = bf16pair(a.y, c.y);        // ... for v+1
            *(uint2*)&T[q * TP + vl] = d;
        }
    }
    __syncthreads();

    unsigned* dstb = xtw + (size_t)b * NV * 16;      // 16 dwords per vertex row
    #pragma unroll
    for (int i = 0; i < 4; ++i) {
        const int vl = i * 64 + w * 16 + (L >> 2);
        const int u4 = L & 3;                // dword-quad within the 64B row
        const int v  = v0 + vl;
        if (v < NV) {
            uint4 d;
            d.x = T[(4 * u4 + 0) * TP + vl];
            d.y = T[(4 * u4 + 1) * TP + vl];
            d.z = T[(4 * u4 + 2) * TP + vl];
            d.w = T[(4 * u4 + 3) * TP + vl];
            *(uint4*)&dstb[(size_t)v * 16 + 4 * u4] = d;
        }
    }
}

// ---------------------------------------------------------------------------
// Kernel 2: conv weight f32 [o][c][j] -> bf16 [o][k=c*9+j]  (GEMM K-order)
// ---------------------------------------------------------------------------
__global__ void __launch_bounds__(256) convert_w_bf16(
    const float* __restrict__ w, unsigned short* __restrict__ wbf)
{
    const int i = blockIdx.x * 256 + threadIdx.x;
    if (i < COUT * CIN * NK) {
        unsigned u = __float_as_uint(w[i]);
        wbf[i] = (unsigned short)((u + 0x7FFFu + ((u >> 16) & 1u)) >> 16);
    }
}

// ---------------------------------------------------------------------------
// Kernel 3: fused gather -> interp (VALU f32) -> conv (MFMA bf16) -> mask.
// Block = 512 thr (8 waves): 16 vertices x 4 batches = 64 cols;
// thread = (col, 4-ch chunk). Gathers issued BEFORE itp staging so their
// latency hides behind the staging + barrier.
// ---------------------------------------------------------------------------
__global__ void __launch_bounds__(512, 4) sparse_conv_mfma(
    const unsigned short* __restrict__ xt, const int* __restrict__ index,
    const float* __restrict__ itp, const unsigned short* __restrict__ wbf,
    const float* __restrict__ bias, float* __restrict__ out)
{
    __shared__ unsigned short Alds[64 * APAD];   // 37.9 KB
    __shared__ float itp_s[16 * 81];             // 5.2 KB
    __shared__ float nz_s[64];

    const int t    = threadIdx.x;
    const int v0   = blockIdx.x * 16;
    const int col  = t & 63;                 // b*16 + vloc
    const int q    = t >> 6;                 // 0..7: channels q*4..q*4+3
    const int c0   = q * 4;
    const int b    = col >> 4;
    const int vloc = col & 15;
    const int v    = min(v0 + vloc, NV - 1);

    // 1) index loads, then the 9 long-latency scattered gathers (early issue)
    int nbr[NK];
    #pragma unroll
    for (int k = 0; k < NK; ++k) nbr[k] = index[v * NK + k];

    uint2 g2[NK];
    const unsigned short* gb = xt + (size_t)b * NV * 32 + c0;
    #pragma unroll
    for (int k = 0; k < NK; ++k)
        g2[k] = *(const uint2*)(gb + (size_t)nbr[k] * 32);

    // 2) stage itp for the block's 16 vertices (coalesced), overlaps gathers
    {
        const size_t ibase = (size_t)v0 * 81;
        #pragma unroll
        for (int i = t; i < 16 * 81; i += 512)
            itp_s[i] = (ibase + i < (size_t)NV * 81) ? itp[ibase + i] : 0.0f;
    }
    if (t < 64) nz_s[t] = 0.0f;
    __syncthreads();

    // 3) unpack + interp (f32, reg-resident)
    unsigned nzbits = 0;
    float g[4][NK];
    #pragma unroll
    for (int k = 0; k < NK; ++k) {
        nzbits |= (g2[k].x | g2[k].y) & 0x7FFF7FFFu;
        g[0][k] = __uint_as_float(g2[k].x << 16);
        g[1][k] = __uint_as_float(g2[k].x & 0xFFFF0000u);
        g[2][k] = __uint_as_float(g2[k].y << 16);
        g[3][k] = __uint_as_float(g2[k].y & 0xFFFF0000u);
    }
    float acc[4][NK];
    #pragma unroll
    for (int cc = 0; cc < 4; ++cc)
        #pragma unroll
        for (int j = 0; j < NK; ++j) acc[cc][j] = 0.0f;
    #pragma unroll
    for (int k = 0; k < NK; ++k) {
        float row[NK];
        #pragma unroll
        for (int j = 0; j < NK; ++j) row[j] = itp_s[vloc * 81 + k * 9 + j];
        #pragma unroll
        for (int cc = 0; cc < 4; ++cc)
            #pragma unroll
            for (int j = 0; j < NK; ++j) acc[cc][j] += g[cc][k] * row[j];
    }

    // 4) pack bf16 -> Alds[col][k], k = (c0+cc)*9 + j (36 contiguous shorts)
    {
        float fl[36];
        #pragma unroll
        for (int cc = 0; cc < 4; ++cc)
            #pragma unroll
            for (int j = 0; j < NK; ++j) fl[cc * 9 + j] = acc[cc][j];
        unsigned* dst = (unsigned*)&Alds[col * APAD + c0 * 9];
        #pragma unroll
        for (int i = 0; i < 18; ++i) dst[i] = bf16pair(fl[2 * i], fl[2 * i + 1]);
    }
    if (nzbits) nz_s[col] = 1.0f;            // benign same-value race
    __syncthreads();

    // 5) MFMA: wave w -> (b = w>>1, o-half = w&1); 16 cols x 16 o, 9 K-steps
    const int wv   = t >> 6;
    const int L    = t & 63;
    const int n16  = L & 15;
    const int quad = L >> 4;
    const int bb   = wv >> 1;
    const int oh   = wv & 1;
    const int colw = bb * 16 + n16;

    f32x4 acc0 = {0.f, 0.f, 0.f, 0.f};
    #pragma unroll
    for (int ks = 0; ks < 9; ++ks) {
        const int ko = ks * 32 + quad * 8;
        const bf16x8 a  = *(const bf16x8*)(wbf + (oh * 16 + n16) * 288 + ko);
        const bf16x8 bf = *(const bf16x8*)(&Alds[colw * APAD + ko]);
        acc0 = __builtin_amdgcn_mfma_f32_16x16x32_bf16(a, bf, acc0, 0, 0, 0);
    }

    const int vv = v0 + n16;
    if (vv < NV) {
        const float m = nz_s[colw];
        float* outb = out + (size_t)bb * (COUT * NV) + vv;
        #pragma unroll
        for (int r = 0; r < 4; ++r) {
            const int o = oh * 16 + quad * 4 + r;
            outb[(size_t)o * NV] = (acc0[r] + bias[o]) * m;
        }
    }
}

// ---------------------------------------------------------------------------
extern "C" void kernel_launch(void* const* d_in, const int* in_sizes, int n_in,
                              void* d_out, int out_size, void* d_ws, size_t ws_size,
                              hipStream_t stream)
{
    const float* x     = (const float*)d_in[0];
    const int*   index = (const int*)  d_in[1];
    const float* itp   = (const float*)d_in[2];
    const float* w     = (const float*)d_in[3];
    const float* bias  = (const float*)d_in[4];
    float*       out   = (float*)d_out;

    unsigned short* xt  = (unsigned short*)d_ws;                 // NV*128*2 B
    unsigned short* wbf = (unsigned short*)((char*)d_ws + (size_t)NV * 128 * 2);

    hipLaunchKernelGGL(convert_w_bf16, dim3((COUT * CIN * NK + 255) / 256),
                       dim3(256), 0, stream, w, wbf);
    const int vtiles = (NV + VT - 1) / VT;   // 161
    hipLaunchKernelGGL(transpose_x_bf16, dim3(vtiles * NBS), dim3(256), 0,
                       stream, x, (unsigned*)xt);
    hipLaunchKernelGGL(sparse_conv_mfma, dim3((NV + 15) / 16), dim3(512), 0,
                       stream, xt, index, itp, wbf, bias, out);
}

// Round 4
// 185.289 us; speedup vs baseline: 1.3723x; 1.3723x over previous
//
#include <hip/hip_runtime.h>

#define NV 40962
#define NK 9
#define CIN 32
#define COUT 32
#define NBS 4
#define VT 256                 // transpose v-tile
#define TP 260                 // transpose LDS row stride (dwords)
#define APAD 296               // Alds row stride (shorts), 288 used

typedef __attribute__((ext_vector_type(8))) short bf16x8;
typedef __attribute__((ext_vector_type(4))) float f32x4;

// round-to-nearest-even f32 -> bf16 pair packed in a dword (a=low, b=high)
__device__ __forceinline__ unsigned bf16pair(float a, float b) {
    unsigned ua = __float_as_uint(a), ub = __float_as_uint(b);
    ua = (ua + 0x7FFFu + ((ua >> 16) & 1u)) >> 16;
    ub = (ub + 0x7FFFu + ((ub >> 16) & 1u)) & 0xFFFF0000u;
    return (ua & 0xFFFFu) | ub;
}

// ---------------------------------------------------------------------------
// Kernel 1: x [128 rows=(b*32+c)][V] f32 -> xt_b[b][v][32ch] bf16.
// Block = (b, 256-v tile): reads are 1KB-contiguous per channel row,
// writes are 1KB-contiguous uint4 streams. LDS holds ch-PAIR dwords.
// ---------------------------------------------------------------------------
__global__ void __launch_bounds__(256) transpose_x_bf16(
    const float* __restrict__ x, unsigned* __restrict__ xtw)
{
    __shared__ unsigned T[16 * TP];          // 16 ch-pairs x 260 dwords = 16.6 KB
    const int b  = blockIdx.x & 3;
    const int v0 = (blockIdx.x >> 2) * VT;
    const int t  = threadIdx.x;
    const int w  = t >> 6;
    const int L  = t & 63;
    const bool full = (v0 + VT <= NV);

    #pragma unroll
    for (int i = 0; i < 4; ++i) {
        const int q = w + 4 * i;             // ch-pair 0..15 (ch 2q, 2q+1)
        const float* rowA = x + (size_t)(b * 32 + 2 * q) * NV;
        const float* rowB = rowA + NV;
        #pragma unroll
        for (int h = 0; h < 2; ++h) {
            const int vl = 128 * h + 2 * L;  // 0..254 (even)
            float2 a, c;
            if (full) {
                a = *(const float2*)(rowA + v0 + vl);
                c = *(const float2*)(rowB + v0 + vl);
            } else {
                const int v = v0 + vl;
                a.x = (v     < NV) ? rowA[v]     : 0.0f;
                a.y = (v + 1 < NV) ? rowA[v + 1] : 0.0f;
                c.x = (v     < NV) ? rowB[v]     : 0.0f;
                c.y = (v + 1 < NV) ? rowB[v + 1] : 0.0f;
            }
            uint2 d;
            d.x = bf16pair(a.x, c.x);        // (ch 2q, 2q+1) for v
            d.y = bf16pair(a.y, c.y);        // ... for v+1
            *(uint2*)&T[q * TP + vl] = d;
        }
    }
    __syncthreads();

    unsigned* dstb = xtw + (size_t)b * NV * 16;      // 16 dwords per vertex row
    #pragma unroll
    for (int i = 0; i < 4; ++i) {
        const int vl = i * 64 + w * 16 + (L >> 2);
        const int u4 = L & 3;                // dword-quad within the 64B row
        const int v  = v0 + vl;
        if (v < NV) {
            uint4 d;
            d.x = T[(4 * u4 + 0) * TP + vl];
            d.y = T[(4 * u4 + 1) * TP + vl];
            d.z = T[(4 * u4 + 2) * TP + vl];
            d.w = T[(4 * u4 + 3) * TP + vl];
            *(uint4*)&dstb[(size_t)v * 16 + 4 * u4] = d;
        }
    }
}

// ---------------------------------------------------------------------------
// Kernel 2: conv weight f32 [o][c][j] -> bf16 [o][k=c*9+j]  (GEMM K-order)
// ---------------------------------------------------------------------------
__global__ void __launch_bounds__(256) convert_w_bf16(
    const float* __restrict__ w, unsigned short* __restrict__ wbf)
{
    const int i = blockIdx.x * 256 + threadIdx.x;
    if (i < COUT * CIN * NK) {
        unsigned u = __float_as_uint(w[i]);
        wbf[i] = (unsigned short)((u + 0x7FFFu + ((u >> 16) & 1u)) >> 16);
    }
}

// ---------------------------------------------------------------------------
// Kernel 3: fused gather -> interp (VALU f32) -> conv (MFMA bf16) -> mask.
// Block = 512 thr (8 waves): 16 vertices x 4 batches = 64 cols;
// thread = (col, 4-ch chunk). Gathers issued BEFORE itp staging so their
// latency hides behind the staging + barrier.
// NOTE: plain __launch_bounds__(512). Round 3's (512,4) clamped VGPR to 64
// and the phase-1 working set spilled (WRITE_SIZE 28->289 MB). Registers
// over occupancy here.
// ---------------------------------------------------------------------------
__global__ void __launch_bounds__(512) sparse_conv_mfma(
    const unsigned short* __restrict__ xt, const int* __restrict__ index,
    const float* __restrict__ itp, const unsigned short* __restrict__ wbf,
    const float* __restrict__ bias, float* __restrict__ out)
{
    __shared__ unsigned short Alds[64 * APAD];   // 37.9 KB
    __shared__ float itp_s[16 * 81];             // 5.2 KB
    __shared__ float nz_s[64];

    const int t    = threadIdx.x;
    const int v0   = blockIdx.x * 16;
    const int col  = t & 63;                 // b*16 + vloc
    const int q    = t >> 6;                 // 0..7: channels q*4..q*4+3
    const int c0   = q * 4;
    const int b    = col >> 4;
    const int vloc = col & 15;
    const int v    = min(v0 + vloc, NV - 1);

    // 1) index loads, then the 9 long-latency scattered gathers (early issue)
    int nbr[NK];
    #pragma unroll
    for (int k = 0; k < NK; ++k) nbr[k] = index[v * NK + k];

    uint2 g2[NK];
    const unsigned short* gb = xt + (size_t)b * NV * 32 + c0;
    #pragma unroll
    for (int k = 0; k < NK; ++k)
        g2[k] = *(const uint2*)(gb + (size_t)nbr[k] * 32);

    // 2) stage itp for the block's 16 vertices (coalesced), overlaps gathers
    {
        const size_t ibase = (size_t)v0 * 81;
        #pragma unroll
        for (int i = t; i < 16 * 81; i += 512)
            itp_s[i] = (ibase + i < (size_t)NV * 81) ? itp[ibase + i] : 0.0f;
    }
    if (t < 64) nz_s[t] = 0.0f;
    __syncthreads();

    // 3) unpack + interp (f32, reg-resident)
    unsigned nzbits = 0;
    float g[4][NK];
    #pragma unroll
    for (int k = 0; k < NK; ++k) {
        nzbits |= (g2[k].x | g2[k].y) & 0x7FFF7FFFu;
        g[0][k] = __uint_as_float(g2[k].x << 16);
        g[1][k] = __uint_as_float(g2[k].x & 0xFFFF0000u);
        g[2][k] = __uint_as_float(g2[k].y << 16);
        g[3][k] = __uint_as_float(g2[k].y & 0xFFFF0000u);
    }
    float acc[4][NK];
    #pragma unroll
    for (int cc = 0; cc < 4; ++cc)
        #pragma unroll
        for (int j = 0; j < NK; ++j) acc[cc][j] = 0.0f;
    #pragma unroll
    for (int k = 0; k < NK; ++k) {
        float row[NK];
        #pragma unroll
        for (int j = 0; j < NK; ++j) row[j] = itp_s[vloc * 81 + k * 9 + j];
        #pragma unroll
        for (int cc = 0; cc < 4; ++cc)
            #pragma unroll
            for (int j = 0; j < NK; ++j) acc[cc][j] += g[cc][k] * row[j];
    }

    // 4) pack bf16 -> Alds[col][k], k = (c0+cc)*9 + j (36 contiguous shorts)
    {
        float fl[36];
        #pragma unroll
        for (int cc = 0; cc < 4; ++cc)
            #pragma unroll
            for (int j = 0; j < NK; ++j) fl[cc * 9 + j] = acc[cc][j];
        unsigned* dst = (unsigned*)&Alds[col * APAD + c0 * 9];
        #pragma unroll
        for (int i = 0; i < 18; ++i) dst[i] = bf16pair(fl[2 * i], fl[2 * i + 1]);
    }
    if (nzbits) nz_s[col] = 1.0f;            // benign same-value race
    __syncthreads();

    // 5) MFMA: wave w -> (b = w>>1, o-half = w&1); 16 cols x 16 o, 9 K-steps
    const int wv   = t >> 6;
    const int L    = t & 63;
    const int n16  = L & 15;
    const int quad = L >> 4;
    const int bb   = wv >> 1;
    const int oh   = wv & 1;
    const int colw = bb * 16 + n16;

    f32x4 acc0 = {0.f, 0.f, 0.f, 0.f};
    #pragma unroll
    for (int ks = 0; ks < 9; ++ks) {
        const int ko = ks * 32 + quad * 8;
        const bf16x8 a  = *(const bf16x8*)(wbf + (oh * 16 + n16) * 288 + ko);
        const bf16x8 bf = *(const bf16x8*)(&Alds[colw * APAD + ko]);
        acc0 = __builtin_amdgcn_mfma_f32_16x16x32_bf16(a, bf, acc0, 0, 0, 0);
    }

    const int vv = v0 + n16;
    if (vv < NV) {
        const float m = nz_s[colw];
        float* outb = out + (size_t)bb * (COUT * NV) + vv;
        #pragma unroll
        for (int r = 0; r < 4; ++r) {
            const int o = oh * 16 + quad * 4 + r;
            outb[(size_t)o * NV] = (acc0[r] + bias[o]) * m;
        }
    }
}

// ---------------------------------------------------------------------------
extern "C" void kernel_launch(void* const* d_in, const int* in_sizes, int n_in,
                              void* d_out, int out_size, void* d_ws, size_t ws_size,
                              hipStream_t stream)
{
    const float* x     = (const float*)d_in[0];
    const int*   index = (const int*)  d_in[1];
    const float* itp   = (const float*)d_in[2];
    const float* w     = (const float*)d_in[3];
    const float* bias  = (const float*)d_in[4];
    float*       out   = (float*)d_out;

    unsigned short* xt  = (unsigned short*)d_ws;                 // NV*128*2 B
    unsigned short* wbf = (unsigned short*)((char*)d_ws + (size_t)NV * 128 * 2);

    hipLaunchKernelGGL(convert_w_bf16, dim3((COUT * CIN * NK + 255) / 256),
                       dim3(256), 0, stream, w, wbf);
    const int vtiles = (NV + VT - 1) / VT;   // 161
    hipLaunchKernelGGL(transpose_x_bf16, dim3(vtiles * NBS), dim3(256), 0,
                       stream, x, (unsigned*)xt);
    hipLaunchKernelGGL(sparse_conv_mfma, dim3((NV + 15) / 16), dim3(512), 0,
                       stream, xt, index, itp, wbf, bias, out);
}

// Round 6
// 156.393 us; speedup vs baseline: 1.6258x; 1.1848x over previous
//
#include <hip/hip_runtime.h>

#define NV 40962
#define NK 9
#define CIN 32
#define COUT 32
#define NBS 4
#define VT 256                 // transpose v-tile
#define TP 260                 // transpose LDS row stride (dwords)
#define APAD 296               // Alds row stride (shorts), 288 used
#define NT 2561                // v-tiles of 16 in main kernel
#define PGRID 768              // persistent blocks (3 per CU)
#define NV81 (NV * 81)

typedef __attribute__((ext_vector_type(8))) short bf16x8;
typedef __attribute__((ext_vector_type(4))) float f32x4;

// round-to-nearest-even f32 -> bf16 pair packed in a dword (a=low, b=high)
__device__ __forceinline__ unsigned bf16pair(float a, float b) {
    unsigned ua = __float_as_uint(a), ub = __float_as_uint(b);
    ua = (ua + 0x7FFFu + ((ua >> 16) & 1u)) >> 16;
    ub = (ub + 0x7FFFu + ((ub >> 16) & 1u)) & 0xFFFF0000u;
    return (ua & 0xFFFFu) | ub;
}

// Block barrier WITHOUT the __syncthreads vmcnt(0) drain: LDS-only drain.
// All cross-wave data in the main loop moves via ds_write (lgkmcnt class);
// in-flight global loads are consumed by their own wave (compiler inserts
// precise vmcnt waits), so they may legally stay in flight across this.
__device__ __forceinline__ void bar_lgkm() {
    asm volatile("s_waitcnt lgkmcnt(0)\n\ts_barrier" ::: "memory");
}

// ---------------------------------------------------------------------------
// Kernel 1: x [128 rows=(b*32+c)][V] f32 -> xt [v][128ch-interleaved] bf16,
// row v = [b0:ch0..31][b1][b2][b3] (256 B). One 256B row serves all 4 b of a
// gather (round-2 layout: FETCH 45 MB vs 75 MB for the b-split layout).
// ---------------------------------------------------------------------------
__global__ void __launch_bounds__(256) transpose_x_bf16(
    const float* __restrict__ x, unsigned* __restrict__ xtw)
{
    __shared__ unsigned T[16 * TP];          // 16 ch-pairs x 260 dwords
    const int b  = blockIdx.x & 3;
    const int v0 = (blockIdx.x >> 2) * VT;
    const int t  = threadIdx.x;
    const int w  = t >> 6;
    const int L  = t & 63;
    const bool full = (v0 + VT <= NV);

    #pragma unroll
    for (int i = 0; i < 4; ++i) {
        const int q = w + 4 * i;             // ch-pair 0..15 (ch 2q, 2q+1)
        const float* rowA = x + (size_t)(b * 32 + 2 * q) * NV;
        const float* rowB = rowA + NV;
        #pragma unroll
        for (int h = 0; h < 2; ++h) {
            const int vl = 128 * h + 2 * L;
            float2 a, c;
            if (full) {
                a = *(const float2*)(rowA + v0 + vl);
                c = *(const float2*)(rowB + v0 + vl);
            } else {
                const int v = v0 + vl;
                a.x = (v     < NV) ? rowA[v]     : 0.0f;
                a.y = (v + 1 < NV) ? rowA[v + 1] : 0.0f;
                c.x = (v     < NV) ? rowB[v]     : 0.0f;
                c.y = (v + 1 < NV) ? rowB[v + 1] : 0.0f;
            }
            uint2 d;
            d.x = bf16pair(a.x, c.x);
            d.y = bf16pair(a.y, c.y);
            *(uint2*)&T[q * TP + vl] = d;
        }
    }
    __syncthreads();

    #pragma unroll
    for (int i = 0; i < 4; ++i) {
        const int vl = i * 64 + w * 16 + (L >> 2);
        const int u4 = L & 3;                // dword-quad within 64B b-segment
        const int v  = v0 + vl;
        if (v < NV) {
            uint4 d;
            d.x = T[(4 * u4 + 0) * TP + vl];
            d.y = T[(4 * u4 + 1) * TP + vl];
            d.z = T[(4 * u4 + 2) * TP + vl];
            d.w = T[(4 * u4 + 3) * TP + vl];
            *(uint4*)&xtw[(size_t)v * 64 + b * 16 + 4 * u4] = d;
        }
    }
}

// ---------------------------------------------------------------------------
// Kernel 2: conv weight f32 [o][c][j] -> bf16 [o][k=c*9+j]  (GEMM K-order)
// ---------------------------------------------------------------------------
__global__ void __launch_bounds__(256) convert_w_bf16(
    const float* __restrict__ w, unsigned short* __restrict__ wbf)
{
    const int i = blockIdx.x * 256 + threadIdx.x;
    if (i < COUT * CIN * NK) {
        unsigned u = __float_as_uint(w[i]);
        wbf[i] = (unsigned short)((u + 0x7FFFu + ((u >> 16) & 1u)) >> 16);
    }
}

// itp global load for a 16-vertex tile, per-element guarded (zero-fill OOB).
// FIX r5->r6: base is tile*16*81 EXACTLY (no min-clamp: the clamp staged a
// shifted vertex range for the last tile and misaligned vloc->itp row).
__device__ __forceinline__ void load_itp(float itpv[6],
                                         const float* __restrict__ itp,
                                         int tile, int t)
{
    const size_t base = (size_t)tile * (16 * 81);
    #pragma unroll
    for (int i = 0; i < 6; ++i) {
        const int o = i * 256 + t;
        itpv[i] = (o < 1296 && base + o < (size_t)NV81) ? itp[base + o] : 0.0f;
    }
}

// stage 1296 itp dwords into padded LDS [vl][k][12] (16B-aligned rows)
__device__ __forceinline__ void stage_itp(float* __restrict__ buf,
                                          const float itpv[6], int t)
{
    #pragma unroll
    for (int i = 0; i < 6; ++i) {
        const int o = i * 256 + t;
        if (o < 1296) {
            const int vl = o / 81;
            const int r  = o - vl * 81;
            const int kk = r / 9;
            const int jj = r - kk * 9;
            buf[vl * 108 + kk * 12 + jj] = itpv[i];
        }
    }
}

// ---------------------------------------------------------------------------
// Kernel 3: persistent pipelined fused kernel. Block = 256 thr (4 waves),
// grid-strides over 16-vertex tiles. Per iter: consume tile t's prefetched
// gathers/itp -> interp -> pack bf16 to Alds; issue tile t+1 gathers + t+2
// idx/itp; lgkm-only barrier; MFMA + store tile t; lgkm-only barrier.
// ---------------------------------------------------------------------------
__global__ void __launch_bounds__(256) sparse_conv_mfma(
    const unsigned short* __restrict__ xt, const int* __restrict__ index,
    const float* __restrict__ itp, const unsigned short* __restrict__ wbf,
    const float* __restrict__ bias, float* __restrict__ out)
{
    __shared__ unsigned short Alds[64 * APAD];   // 37.9 KB
    __shared__ float itp_s[2][16 * 108];         // 13.8 KB (padded rows)
    __shared__ unsigned nzv[4][64];              // 1 KB

    const int t    = threadIdx.x;
    const int col  = t & 63;                 // b*16 + vloc
    const int q    = t >> 6;                 // ch-group: c = q*8 .. q*8+7
    const int c0   = q * 8;
    const int b    = col >> 4;
    const int vloc = col & 15;

    // ---------------- prologue: fill the pipeline ----------------
    int tile = blockIdx.x;
    int idxc[NK];
    {
        const int v = min(tile * 16 + vloc, NV - 1);
        #pragma unroll
        for (int k = 0; k < NK; ++k) idxc[k] = index[v * NK + k];
    }
    float itpv[6];
    load_itp(itpv, itp, tile, t);            // tile0's itp
    uint4 gath[NK];
    {
        const unsigned short* gb = xt + b * 32 + c0;
        #pragma unroll
        for (int k = 0; k < NK; ++k)
            gath[k] = *(const uint4*)(gb + (size_t)idxc[k] * 128);
    }
    {   // idx for tile+PGRID
        const int tn = min(tile + PGRID, NT - 1);
        const int v  = min(tn * 16 + vloc, NV - 1);
        #pragma unroll
        for (int k = 0; k < NK; ++k) idxc[k] = index[v * NK + k];
    }
    stage_itp(itp_s[0], itpv, t);            // tile0 -> buf0
    load_itp(itpv, itp, min(tile + PGRID, NT - 1), t);   // itp(t+PGRID)
    bar_lgkm();

    int p = 0;
    for (; tile < NT; tile += PGRID) {
        const int v0 = tile * 16;

        // ---- B: stage itp(t+1) into buf p^1; consume gath(t) -> Alds ----
        stage_itp(itp_s[p ^ 1], itpv, t);

        const float* ibuf = itp_s[p];
        unsigned nzbits = 0;
        #pragma unroll
        for (int half = 0; half < 2; ++half) {
            float g[4][NK];
            #pragma unroll
            for (int k = 0; k < NK; ++k) {
                const unsigned lo = half ? gath[k].z : gath[k].x;
                const unsigned hi = half ? gath[k].w : gath[k].y;
                nzbits |= (lo | hi) & 0x7FFF7FFFu;
                g[0][k] = __uint_as_float(lo << 16);
                g[1][k] = __uint_as_float(lo & 0xFFFF0000u);
                g[2][k] = __uint_as_float(hi << 16);
                g[3][k] = __uint_as_float(hi & 0xFFFF0000u);
            }
            float acc[4][NK];
            #pragma unroll
            for (int cc = 0; cc < 4; ++cc)
                #pragma unroll
                for (int j = 0; j < NK; ++j) acc[cc][j] = 0.0f;
            #pragma unroll
            for (int k = 0; k < NK; ++k) {
                const float4 ra = *(const float4*)&ibuf[vloc * 108 + k * 12];
                const float4 rb = *(const float4*)&ibuf[vloc * 108 + k * 12 + 4];
                const float  r8 = ibuf[vloc * 108 + k * 12 + 8];
                const float row[NK] = {ra.x, ra.y, ra.z, ra.w,
                                       rb.x, rb.y, rb.z, rb.w, r8};
                #pragma unroll
                for (int cc = 0; cc < 4; ++cc)
                    #pragma unroll
                    for (int j = 0; j < NK; ++j)
                        acc[cc][j] += g[cc][k] * row[j];
            }
            // pack to Alds[col][(c0+half*4+cc)*9 + j] (36 contiguous shorts)
            unsigned* dst = (unsigned*)&Alds[col * APAD + (c0 + half * 4) * 9];
            float flat[36];
            #pragma unroll
            for (int cc = 0; cc < 4; ++cc)
                #pragma unroll
                for (int j = 0; j < NK; ++j) flat[cc * 9 + j] = acc[cc][j];
            #pragma unroll
            for (int i = 0; i < 18; ++i)
                dst[i] = bf16pair(flat[2 * i], flat[2 * i + 1]);
        }
        nzv[q][col] = nzbits;                // own slot: no init barrier needed

        // ---- C: issue tile t+1 gathers; tile t+2 idx + itp loads ----
        {
            const unsigned short* gb = xt + b * 32 + c0;
            #pragma unroll
            for (int k = 0; k < NK; ++k)
                gath[k] = *(const uint4*)(gb + (size_t)idxc[k] * 128);
        }
        {
            const int t2 = min(tile + 2 * PGRID, NT - 1);
            const int v  = min(t2 * 16 + vloc, NV - 1);
            #pragma unroll
            for (int k = 0; k < NK; ++k) idxc[k] = index[v * NK + k];
            load_itp(itpv, itp, t2, t);
        }

        bar_lgkm();                          // E1: Alds/nzv/itp(t+1) visible

        // ---- D: MFMA + store tile t ----
        {
            const int dn = col & 15;         // output col within b-tile (= v)
            const int dq = col >> 4;         // K-quad / output row group
            const int db = q;                // wave -> batch
            const int colw = db * 16 + dn;

            f32x4 a0 = {0.f, 0.f, 0.f, 0.f};
            f32x4 a1 = {0.f, 0.f, 0.f, 0.f};
            #pragma unroll
            for (int ks = 0; ks < 9; ++ks) {
                const int ko = ks * 32 + dq * 8;
                const bf16x8 wa = *(const bf16x8*)(wbf + dn * 288 + ko);
                const bf16x8 wb = *(const bf16x8*)(wbf + (dn + 16) * 288 + ko);
                const bf16x8 bf = *(const bf16x8*)(&Alds[colw * APAD + ko]);
                a0 = __builtin_amdgcn_mfma_f32_16x16x32_bf16(wa, bf, a0, 0, 0, 0);
                a1 = __builtin_amdgcn_mfma_f32_16x16x32_bf16(wb, bf, a1, 0, 0, 0);
            }

            const unsigned nz = nzv[0][colw] | nzv[1][colw] |
                                nzv[2][colw] | nzv[3][colw];
            const float m = nz ? 1.0f : 0.0f;
            const int vv = v0 + dn;
            if (vv < NV) {
                float* outb = out + (size_t)db * (COUT * NV) + vv;
                #pragma unroll
                for (int r = 0; r < 4; ++r) {
                    const int o = dq * 4 + r;
                    outb[(size_t)o * NV]        = (a0[r] + bias[o]) * m;
                    outb[(size_t)(o + 16) * NV] = (a1[r] + bias[o + 16]) * m;
                }
            }
        }

        bar_lgkm();                          // E2: Alds reads done before reuse
        p ^= 1;
    }
}

// ---------------------------------------------------------------------------
extern "C" void kernel_launch(void* const* d_in, const int* in_sizes, int n_in,
                              void* d_out, int out_size, void* d_ws, size_t ws_size,
                              hipStream_t stream)
{
    const float* x     = (const float*)d_in[0];
    const int*   index = (const int*)  d_in[1];
    const float* itp   = (const float*)d_in[2];
    const float* w     = (const float*)d_in[3];
    const float* bias  = (const float*)d_in[4];
    float*       out   = (float*)d_out;

    unsigned short* xt  = (unsigned short*)d_ws;                 // NV*128*2 B
    unsigned short* wbf = (unsigned short*)((char*)d_ws + (size_t)NV * 128 * 2);

    hipLaunchKernelGGL(convert_w_bf16, dim3((COUT * CIN * NK + 255) / 256),
                       dim3(256), 0, stream, w, wbf);
    const int vtiles = (NV + VT - 1) / VT;   // 161
    hipLaunchKernelGGL(transpose_x_bf16, dim3(vtiles * NBS), dim3(256), 0,
                       stream, x, (unsigned*)xt);
    hipLaunchKernelGGL(sparse_conv_mfma, dim3(PGRID), dim3(256), 0,
                       stream, xt, index, itp, wbf, bias, out);
}

// Round 7
// 145.770 us; speedup vs baseline: 1.7443x; 1.0729x over previous
//
#include <hip/hip_runtime.h>

#define NV 40962
#define NK 9
#define CIN 32
#define COUT 32
#define NBS 4
#define VT 256                 // transpose v-tile
#define TP 260                 // transpose LDS row stride (dwords)
#define APAD 296               // Alds row stride (shorts): 592B = 37x16B (odd 16B-stride -> conflict-free b128)
#define NT 2561                // v-tiles of 16 in main kernel
#define PGRID 512              // persistent blocks (2 per CU, all co-resident)
#define NV81 (NV * 81)

typedef __attribute__((ext_vector_type(8))) short bf16x8;
typedef __attribute__((ext_vector_type(4))) float f32x4;

// round-to-nearest-even f32 -> bf16 pair packed in a dword (a=low, b=high)
__device__ __forceinline__ unsigned bf16pair(float a, float b) {
    unsigned ua = __float_as_uint(a), ub = __float_as_uint(b);
    ua = (ua + 0x7FFFu + ((ua >> 16) & 1u)) >> 16;
    ub = (ub + 0x7FFFu + ((ub >> 16) & 1u)) & 0xFFFF0000u;
    return (ua & 0xFFFFu) | ub;
}

// Block barrier WITHOUT the __syncthreads vmcnt(0) drain: LDS-only drain.
// All cross-wave data in the main loop moves via ds_write (lgkmcnt class);
// in-flight global loads are consumed by their own wave (compiler inserts
// precise vmcnt waits), so they may legally stay in flight across this.
__device__ __forceinline__ void bar_lgkm() {
    asm volatile("s_waitcnt lgkmcnt(0)\n\ts_barrier" ::: "memory");
}

// ---------------------------------------------------------------------------
// Kernel 1: x [128 rows=(b*32+c)][V] f32 -> xt [v][128ch-interleaved] bf16,
// row v = [b0:ch0..31][b1][b2][b3] (256 B). One 256B row serves all 4 b of a
// gather.
// ---------------------------------------------------------------------------
__global__ void __launch_bounds__(256) transpose_x_bf16(
    const float* __restrict__ x, unsigned* __restrict__ xtw)
{
    __shared__ unsigned T[16 * TP];          // 16 ch-pairs x 260 dwords
    const int b  = blockIdx.x & 3;
    const int v0 = (blockIdx.x >> 2) * VT;
    const int t  = threadIdx.x;
    const int w  = t >> 6;
    const int L  = t & 63;
    const bool full = (v0 + VT <= NV);

    #pragma unroll
    for (int i = 0; i < 4; ++i) {
        const int q = w + 4 * i;             // ch-pair 0..15 (ch 2q, 2q+1)
        const float* rowA = x + (size_t)(b * 32 + 2 * q) * NV;
        const float* rowB = rowA + NV;
        #pragma unroll
        for (int h = 0; h < 2; ++h) {
            const int vl = 128 * h + 2 * L;
            float2 a, c;
            if (full) {
                a = *(const float2*)(rowA + v0 + vl);
                c = *(const float2*)(rowB + v0 + vl);
            } else {
                const int v = v0 + vl;
                a.x = (v     < NV) ? rowA[v]     : 0.0f;
                a.y = (v + 1 < NV) ? rowA[v + 1] : 0.0f;
                c.x = (v     < NV) ? rowB[v]     : 0.0f;
                c.y = (v + 1 < NV) ? rowB[v + 1] : 0.0f;
            }
            uint2 d;
            d.x = bf16pair(a.x, c.x);
            d.y = bf16pair(a.y, c.y);
            *(uint2*)&T[q * TP + vl] = d;
        }
    }
    __syncthreads();

    #pragma unroll
    for (int i = 0; i < 4; ++i) {
        const int vl = i * 64 + w * 16 + (L >> 2);
        const int u4 = L & 3;                // dword-quad within 64B b-segment
        const int v  = v0 + vl;
        if (v < NV) {
            uint4 d;
            d.x = T[(4 * u4 + 0) * TP + vl];
            d.y = T[(4 * u4 + 1) * TP + vl];
            d.z = T[(4 * u4 + 2) * TP + vl];
            d.w = T[(4 * u4 + 3) * TP + vl];
            *(uint4*)&xtw[(size_t)v * 64 + b * 16 + 4 * u4] = d;
        }
    }
}

// ---------------------------------------------------------------------------
// Kernel 2: conv weight f32 [o][c][j] -> bf16 [o][k=c*9+j]  (GEMM K-order)
// ---------------------------------------------------------------------------
__global__ void __launch_bounds__(256) convert_w_bf16(
    const float* __restrict__ w, unsigned short* __restrict__ wbf)
{
    const int i = blockIdx.x * 256 + threadIdx.x;
    if (i < COUT * CIN * NK) {
        unsigned u = __float_as_uint(w[i]);
        wbf[i] = (unsigned short)((u + 0x7FFFu + ((u >> 16) & 1u)) >> 16);
    }
}

// itp global load for a 16-vertex tile, per-element guarded (zero-fill OOB).
__device__ __forceinline__ void load_itp(float itpv[3],
                                         const float* __restrict__ itp,
                                         int tile, int t)
{
    const size_t base = (size_t)tile * (16 * 81);
    #pragma unroll
    for (int i = 0; i < 3; ++i) {
        const int o = i * 512 + t;
        itpv[i] = (o < 1296 && base + o < (size_t)NV81) ? itp[base + o] : 0.0f;
    }
}

// stage 1296 itp dwords into padded LDS [vl][k][12] (16B-aligned rows)
__device__ __forceinline__ void stage_itp(float* __restrict__ buf,
                                          const float itpv[3], int t)
{
    #pragma unroll
    for (int i = 0; i < 3; ++i) {
        const int o = i * 512 + t;
        if (o < 1296) {
            const int vl = o / 81;
            const int r  = o - vl * 81;
            const int kk = r / 9;
            const int jj = r - kk * 9;
            buf[vl * 108 + kk * 12 + jj] = itpv[i];
        }
    }
}

// ---------------------------------------------------------------------------
// Kernel 3: persistent pipelined fused kernel. Block = 512 thr (8 waves),
// grid-strides over 16-vertex tiles. Thread = (col = b*16+vloc, q = 4-ch
// group) in phase B; wave = (batch, o-half) in phase D. Per iter:
//   B: consume prefetched gathers+itp -> interp -> pack bf16 to Alds
//   C: issue tile t+1 gathers + t+2 idx/itp (latency covered by ~1 iter)
//   E1 (lgkm barrier) ; D: MFMA + store ; E2 (lgkm barrier)
// 512-thr split keeps VGPR ~100 (r4: 92) -> 2 blocks x 8 waves = 16 w/CU,
// vs r6's 188 VGPR / 8 w/CU.
// ---------------------------------------------------------------------------
__global__ void __launch_bounds__(512) sparse_conv_mfma(
    const unsigned short* __restrict__ xt, const int* __restrict__ index,
    const float* __restrict__ itp, const unsigned short* __restrict__ wbf,
    const float* __restrict__ bias, float* __restrict__ out)
{
    __shared__ unsigned short Alds[64 * APAD];   // 37.9 KB
    __shared__ float itp_s[2][16 * 108];         // 13.8 KB (padded rows)
    __shared__ unsigned nzv[8][64];              // 2 KB

    const int t    = threadIdx.x;
    const int col  = t & 63;                 // b*16 + vloc
    const int q    = t >> 6;                 // 0..7: channels q*4..q*4+3
    const int c0   = q * 4;
    const int b    = col >> 4;
    const int vloc = col & 15;

    // ---------------- prologue: fill the pipeline ----------------
    int tile = blockIdx.x;
    int idxc[NK];
    {
        const int v = min(tile * 16 + vloc, NV - 1);
        #pragma unroll
        for (int k = 0; k < NK; ++k) idxc[k] = index[v * NK + k];
    }
    float itpv[3];
    load_itp(itpv, itp, tile, t);            // tile0's itp
    uint2 gath[NK];
    {
        const unsigned short* gb = xt + b * 32 + c0;
        #pragma unroll
        for (int k = 0; k < NK; ++k)
            gath[k] = *(const uint2*)(gb + (size_t)idxc[k] * 128);
    }
    {   // idx for tile+PGRID
        const int tn = min(tile + PGRID, NT - 1);
        const int v  = min(tn * 16 + vloc, NV - 1);
        #pragma unroll
        for (int k = 0; k < NK; ++k) idxc[k] = index[v * NK + k];
    }
    stage_itp(itp_s[0], itpv, t);            // tile0 -> buf0
    load_itp(itpv, itp, min(tile + PGRID, NT - 1), t);   // itp(t+PGRID)
    bar_lgkm();

    int p = 0;
    for (; tile < NT; tile += PGRID) {
        const int v0 = tile * 16;

        // ---- B: stage itp(t+1) into buf p^1; consume gath(t) -> Alds ----
        stage_itp(itp_s[p ^ 1], itpv, t);

        const float* ibuf = itp_s[p];
        unsigned nzbits = 0;
        float g[4][NK];
        #pragma unroll
        for (int k = 0; k < NK; ++k) {
            nzbits |= (gath[k].x | gath[k].y) & 0x7FFF7FFFu;
            g[0][k] = __uint_as_float(gath[k].x << 16);
            g[1][k] = __uint_as_float(gath[k].x & 0xFFFF0000u);
            g[2][k] = __uint_as_float(gath[k].y << 16);
            g[3][k] = __uint_as_float(gath[k].y & 0xFFFF0000u);
        }
        float acc[4][NK];
        #pragma unroll
        for (int cc = 0; cc < 4; ++cc)
            #pragma unroll
            for (int j = 0; j < NK; ++j) acc[cc][j] = 0.0f;
        #pragma unroll
        for (int k = 0; k < NK; ++k) {
            const float4 ra = *(const float4*)&ibuf[vloc * 108 + k * 12];
            const float4 rb = *(const float4*)&ibuf[vloc * 108 + k * 12 + 4];
            const float  r8 = ibuf[vloc * 108 + k * 12 + 8];
            const float row[NK] = {ra.x, ra.y, ra.z, ra.w,
                                   rb.x, rb.y, rb.z, rb.w, r8};
            #pragma unroll
            for (int cc = 0; cc < 4; ++cc)
                #pragma unroll
                for (int j = 0; j < NK; ++j)
                    acc[cc][j] += g[cc][k] * row[j];
        }
        // pack to Alds[col][(c0+cc)*9 + j] (36 contiguous shorts), inline
        // static indexing (f = cc*9+j pairs) -- no flat[] temp array
        {
            unsigned* dst = (unsigned*)&Alds[col * APAD + c0 * 9];
            #pragma unroll
            for (int i = 0; i < 18; ++i) {
                const int f0 = 2 * i, f1 = 2 * i + 1;
                dst[i] = bf16pair(acc[f0 / 9][f0 % 9], acc[f1 / 9][f1 % 9]);
            }
        }
        nzv[q][col] = nzbits;                // own slot: no init barrier needed

        // ---- C: issue tile t+1 gathers; tile t+2 idx + itp loads ----
        {
            const unsigned short* gb = xt + b * 32 + c0;
            #pragma unroll
            for (int k = 0; k < NK; ++k)
                gath[k] = *(const uint2*)(gb + (size_t)idxc[k] * 128);
        }
        {
            const int t2 = min(tile + 2 * PGRID, NT - 1);
            const int v  = min(t2 * 16 + vloc, NV - 1);
            #pragma unroll
            for (int k = 0; k < NK; ++k) idxc[k] = index[v * NK + k];
            load_itp(itpv, itp, t2, t);
        }

        bar_lgkm();                          // E1: Alds/nzv/itp(t+1) visible

        // ---- D: MFMA + store tile t ----
        {
            const int dn = vloc;             // output col within b-tile (= v)
            const int dq = col >> 4;         // K-quad / output row group
            const int bb = q >> 1;           // wave -> batch
            const int oh = q & 1;            // wave -> o-half
            const int colw = bb * 16 + dn;

            f32x4 a0 = {0.f, 0.f, 0.f, 0.f};
            #pragma unroll
            for (int ks = 0; ks < 9; ++ks) {
                const int ko = ks * 32 + dq * 8;
                const bf16x8 wa = *(const bf16x8*)(wbf + (oh * 16 + dn) * 288 + ko);
                const bf16x8 bf = *(const bf16x8*)(&Alds[colw * APAD + ko]);
                a0 = __builtin_amdgcn_mfma_f32_16x16x32_bf16(wa, bf, a0, 0, 0, 0);
            }

            const unsigned nz = nzv[0][colw] | nzv[1][colw] |
                                nzv[2][colw] | nzv[3][colw] |
                                nzv[4][colw] | nzv[5][colw] |
                                nzv[6][colw] | nzv[7][colw];
            const float m = nz ? 1.0f : 0.0f;
            const int vv = v0 + dn;
            if (vv < NV) {
                float* outb = out + (size_t)bb * (COUT * NV) + vv;
                #pragma unroll
                for (int r = 0; r < 4; ++r) {
                    const int o = oh * 16 + dq * 4 + r;
                    outb[(size_t)o * NV] = (a0[r] + bias[o]) * m;
                }
            }
        }

        bar_lgkm();                          // E2: Alds reads done before reuse
        p ^= 1;
    }
}

// ---------------------------------------------------------------------------
extern "C" void kernel_launch(void* const* d_in, const int* in_sizes, int n_in,
                              void* d_out, int out_size, void* d_ws, size_t ws_size,
                              hipStream_t stream)
{
    const float* x     = (const float*)d_in[0];
    const int*   index = (const int*)  d_in[1];
    const float* itp   = (const float*)d_in[2];
    const float* w     = (const float*)d_in[3];
    const float* bias  = (const float*)d_in[4];
    float*       out   = (float*)d_out;

    unsigned short* xt  = (unsigned short*)d_ws;                 // NV*128*2 B
    unsigned short* wbf = (unsigned short*)((char*)d_ws + (size_t)NV * 128 * 2);

    hipLaunchKernelGGL(convert_w_bf16, dim3((COUT * CIN * NK + 255) / 256),
                       dim3(256), 0, stream, w, wbf);
    const int vtiles = (NV + VT - 1) / VT;   // 161
    hipLaunchKernelGGL(transpose_x_bf16, dim3(vtiles * NBS), dim3(256), 0,
                       stream, x, (unsigned*)xt);
    hipLaunchKernelGGL(sparse_conv_mfma, dim3(PGRID), dim3(512), 0,
                       stream, xt, index, itp, wbf, bias, out);
}

// Round 8
// 139.720 us; speedup vs baseline: 1.8199x; 1.0433x over previous
//
#include <hip/hip_runtime.h>

#define NV 40962
#define NK 9
#define CIN 32
#define COUT 32
#define NBS 4
#define VT 256                 // transpose v-tile
#define TP 260                 // transpose LDS row stride (dwords)
#define NT 2561                // v-tiles of 16 in main kernel
#define PGRID 512              // persistent blocks (2 per CU, all co-resident)
#define NV81 (NV * 81)
#define NV9  (NV * 9)

typedef __attribute__((ext_vector_type(8))) short bf16x8;
typedef __attribute__((ext_vector_type(4))) float f32x4;

// round-to-nearest-even f32 -> bf16 pair packed in a dword (a=low, b=high)
__device__ __forceinline__ unsigned bf16pair(float a, float b) {
    unsigned ua = __float_as_uint(a), ub = __float_as_uint(b);
    ua = (ua + 0x7FFFu + ((ua >> 16) & 1u)) >> 16;
    ub = (ub + 0x7FFFu + ((ub >> 16) & 1u)) & 0xFFFF0000u;
    return (ua & 0xFFFFu) | ub;
}

// Block barrier WITHOUT the __syncthreads vmcnt(0) drain: LDS-only drain.
// All cross-wave data moves via ds_write (lgkmcnt); in-flight global loads
// are consumed by their issuing wave (compiler inserts precise vmcnt).
__device__ __forceinline__ void bar_lgkm() {
    asm volatile("s_waitcnt lgkmcnt(0)\n\ts_barrier" ::: "memory");
}

// ---------------------------------------------------------------------------
// Kernel 1: x [128 rows=(b*32+c)][V] f32 -> xt [v][b0|b1|b2|b3 x 32ch] bf16
// (256 B/row; one row serves all 4 batches of a gather).
// ---------------------------------------------------------------------------
__global__ void __launch_bounds__(256) transpose_x_bf16(
    const float* __restrict__ x, unsigned* __restrict__ xtw)
{
    __shared__ unsigned T[16 * TP];
    const int b  = blockIdx.x & 3;
    const int v0 = (blockIdx.x >> 2) * VT;
    const int t  = threadIdx.x;
    const int w  = t >> 6;
    const int L  = t & 63;
    const bool full = (v0 + VT <= NV);

    #pragma unroll
    for (int i = 0; i < 4; ++i) {
        const int q = w + 4 * i;             // ch-pair 0..15 (ch 2q, 2q+1)
        const float* rowA = x + (size_t)(b * 32 + 2 * q) * NV;
        const float* rowB = rowA + NV;
        #pragma unroll
        for (int h = 0; h < 2; ++h) {
            const int vl = 128 * h + 2 * L;
            float2 a, c;
            if (full) {
                a = *(const float2*)(rowA + v0 + vl);
                c = *(const float2*)(rowB + v0 + vl);
            } else {
                const int v = v0 + vl;
                a.x = (v     < NV) ? rowA[v]     : 0.0f;
                a.y = (v + 1 < NV) ? rowA[v + 1] : 0.0f;
                c.x = (v     < NV) ? rowB[v]     : 0.0f;
                c.y = (v + 1 < NV) ? rowB[v + 1] : 0.0f;
            }
            uint2 d;
            d.x = bf16pair(a.x, c.x);
            d.y = bf16pair(a.y, c.y);
            *(uint2*)&T[q * TP + vl] = d;
        }
    }
    __syncthreads();

    #pragma unroll
    for (int i = 0; i < 4; ++i) {
        const int vl = i * 64 + w * 16 + (L >> 2);
        const int u4 = L & 3;
        const int v  = v0 + vl;
        if (v < NV) {
            uint4 d;
            d.x = T[(4 * u4 + 0) * TP + vl];
            d.y = T[(4 * u4 + 1) * TP + vl];
            d.z = T[(4 * u4 + 2) * TP + vl];
            d.w = T[(4 * u4 + 3) * TP + vl];
            *(uint4*)&xtw[(size_t)v * 64 + b * 16 + 4 * u4] = d;
        }
    }
}

// itp global load for a 16-vertex tile (1296 dwords), per-element guarded.
__device__ __forceinline__ void load_itp(float itpv[3],
                                         const float* __restrict__ itp,
                                         int tile, int t)
{
    const size_t base = (size_t)tile * 1296;
    #pragma unroll
    for (int i = 0; i < 3; ++i) {
        const int o = i * 512 + t;
        itpv[i] = (o < 1296 && base + o < (size_t)NV81) ? itp[base + o] : 0.0f;
    }
}

// stage 1296 itp dwords into padded LDS [vl][k][12]
__device__ __forceinline__ void stage_itp(float* __restrict__ buf,
                                          const float itpv[3], int t)
{
    #pragma unroll
    for (int i = 0; i < 3; ++i) {
        const int o = i * 512 + t;
        if (o < 1296) {
            const int vl = o / 81;
            const int r  = o - vl * 81;
            const int kk = r / 9;
            const int jj = r - kk * 9;
            buf[vl * 108 + kk * 12 + jj] = itpv[i];
        }
    }
}

// idx global load for a tile (144 ints via threads t<144), guarded
__device__ __forceinline__ int load_idx(const int* __restrict__ index,
                                        int tile, int t)
{
    int r = 0;
    if (t < 144) {
        const size_t base = (size_t)tile * 144 + t;
        r = (base < (size_t)NV9) ? index[base] : 0;
    }
    return r;
}

// ---------------------------------------------------------------------------
// Kernel 2: persistent pipelined fused kernel. 512 thr (8 waves), 2 blk/CU.
// LDS (65.4 KB): Alds [36 kchunks][64 cols][16B] (D-reads conflict-free
// b128), Wlds [36 kchunks][32 o][16B] (staged once/block from f32 w), itp_s
// single-buffer (staged during D), idx_s double-buffer, nzv.
// Iter: B (consume gathers+itp -> interp -> pack Alds) ; C (issue t+1
// gathers from idx_s) ; E1 ; D (MFMA+store, stage itp/idx for later tiles,
// issue +2P/+3P loads) ; E2.
// ---------------------------------------------------------------------------
__global__ void __launch_bounds__(512) sparse_conv_mfma(
    const unsigned short* __restrict__ xt, const int* __restrict__ index,
    const float* __restrict__ itp, const float* __restrict__ w,
    const float* __restrict__ bias, float* __restrict__ out)
{
    __shared__ unsigned short Alds[36 * 64 * 8];   // 36864 B
    __shared__ unsigned short Wlds[36 * 32 * 8];   // 18432 B
    __shared__ float itp_s[16 * 108];              //  6912 B
    __shared__ int   idx_s[2][144];                //  1152 B
    __shared__ unsigned nzv[8][64];                //  2048 B

    const int t    = threadIdx.x;
    const int col  = t & 63;                 // b*16 + vloc
    const int q    = t >> 6;                 // wave: ch-group c = 4q..4q+3
    const int b    = col >> 4;
    const int vloc = col & 15;
    const unsigned short* gb = xt + b * 32 + q * 4;

    // ---------------- prologue ----------------
    int tile = blockIdx.x;

    // stage W: chunk c=(ks*4+dq) holds W[o][c*8 .. c*8+8) as 16B per o
    #pragma unroll
    for (int r = 0; r < 3; ++r) {
        const int j = t + r * 512;
        if (j < 1152) {
            const int o = j & 31;
            const int c = j >> 5;
            const float4 f0 = *(const float4*)(w + o * 288 + c * 8);
            const float4 f1 = *(const float4*)(w + o * 288 + c * 8 + 4);
            uint4 d;
            d.x = bf16pair(f0.x, f0.y); d.y = bf16pair(f0.z, f0.w);
            d.z = bf16pair(f1.x, f1.y); d.w = bf16pair(f1.z, f1.w);
            *(uint4*)&Wlds[(c * 32 + o) * 8] = d;
        }
    }
    {   // idx(t0)->idx_s[0], idx(t0+P)->idx_s[1]
        const int i0 = load_idx(index, tile, t);
        const int i1 = load_idx(index, min(tile + PGRID, NT - 1), t);
        if (t < 144) { idx_s[0][t] = i0; idx_s[1][t] = i1; }
    }
    float itpv[3];
    load_itp(itpv, itp, tile, t);
    stage_itp(itp_s, itpv, t);               // itp(t0) -> itp_s
    bar_lgkm();

    uint2 gath[NK];
    #pragma unroll
    for (int k = 0; k < NK; ++k) {           // gathers(t0)
        const int nbr = idx_s[0][vloc * 9 + k];
        gath[k] = *(const uint2*)(gb + (size_t)nbr * 128);
    }
    load_itp(itpv, itp, min(tile + PGRID, NT - 1), t);       // for D(t0)
    int idxn = load_idx(index, min(tile + 2 * PGRID, NT - 1), t);
    int cur = 0;

    for (; tile < NT; tile += PGRID) {
        // ---- B: consume gathers+itp -> interp -> pack Alds ----
        unsigned nzbits = 0;
        float acc[4][NK];
        #pragma unroll
        for (int cc = 0; cc < 4; ++cc)
            #pragma unroll
            for (int j = 0; j < NK; ++j) acc[cc][j] = 0.0f;
        #pragma unroll
        for (int k = 0; k < NK; ++k) {
            const unsigned lo = gath[k].x, hi = gath[k].y;
            nzbits |= (lo | hi) & 0x7FFF7FFFu;
            const float g0 = __uint_as_float(lo << 16);
            const float g1 = __uint_as_float(lo & 0xFFFF0000u);
            const float g2 = __uint_as_float(hi << 16);
            const float g3 = __uint_as_float(hi & 0xFFFF0000u);
            const float4 ra = *(const float4*)&itp_s[vloc * 108 + k * 12];
            const float4 rb = *(const float4*)&itp_s[vloc * 108 + k * 12 + 4];
            const float  r8 = itp_s[vloc * 108 + k * 12 + 8];
            const float row[NK] = {ra.x, ra.y, ra.z, ra.w,
                                   rb.x, rb.y, rb.z, rb.w, r8};
            #pragma unroll
            for (int j = 0; j < NK; ++j) {
                acc[0][j] += g0 * row[j];
                acc[1][j] += g1 * row[j];
                acc[2][j] += g2 * row[j];
                acc[3][j] += g3 * row[j];
            }
        }
        // pack: global k = 36q + 4*i2 .. +4 -> chunk (9q+i2)>>1, 8B half
        #pragma unroll
        for (int i2 = 0; i2 < 9; ++i2) {
            const int k0 = 4 * i2;
            const int chunk = (9 * q + i2) >> 1;
            const int off = 4 * ((q + i2) & 1);      // shorts
            uint2 d;
            d.x = bf16pair(acc[k0 / 9][k0 % 9],
                           acc[(k0 + 1) / 9][(k0 + 1) % 9]);
            d.y = bf16pair(acc[(k0 + 2) / 9][(k0 + 2) % 9],
                           acc[(k0 + 3) / 9][(k0 + 3) % 9]);
            *(uint2*)&Alds[(chunk * 64 + col) * 8 + off] = d;
        }
        nzv[q][col] = nzbits;

        // ---- C: issue gathers(t+P) from idx_s[cur^1] ----
        #pragma unroll
        for (int k = 0; k < NK; ++k) {
            const int nbr = idx_s[cur ^ 1][vloc * 9 + k];
            gath[k] = *(const uint2*)(gb + (size_t)nbr * 128);
        }

        bar_lgkm();                          // E1

        // ---- D: MFMA + store tile; pipeline maintenance ----
        {
            const int dn = vloc;             // output col (v) and A-row (o)
            const int dq = col >> 4;         // K-quad
            const int bb = q >> 1;
            const int oh = q & 1;
            const int colw = bb * 16 + dn;

            f32x4 a0 = {0.f, 0.f, 0.f, 0.f};
            #pragma unroll
            for (int ks = 0; ks < 9; ++ks) {
                const int ch = ks * 4 + dq;
                const bf16x8 wa = *(const bf16x8*)&Wlds[(ch * 32 + oh * 16 + dn) * 8];
                const bf16x8 bf = *(const bf16x8*)&Alds[(ch * 64 + colw) * 8];
                a0 = __builtin_amdgcn_mfma_f32_16x16x32_bf16(wa, bf, a0, 0, 0, 0);
            }

            const unsigned nz = nzv[0][colw] | nzv[1][colw] |
                                nzv[2][colw] | nzv[3][colw] |
                                nzv[4][colw] | nzv[5][colw] |
                                nzv[6][colw] | nzv[7][colw];
            const float m = nz ? 1.0f : 0.0f;
            const int vv = tile * 16 + dn;
            if (vv < NV) {
                float* outb = out + (size_t)bb * (COUT * NV) + vv;
                #pragma unroll
                for (int r = 0; r < 4; ++r) {
                    const int o = oh * 16 + dq * 4 + r;
                    outb[(size_t)o * NV] = (a0[r] + bias[o]) * m;
                }
            }
        }
        // stage itp(t+P) (E1 guarantees B-reads of itp(t) are done)
        stage_itp(itp_s, itpv, t);
        if (t < 144) idx_s[cur][t] = idxn;   // idx(t+2P)
        // issue far-ahead loads (consumed 1..2 iterations later)
        load_itp(itpv, itp, min(tile + 2 * PGRID, NT - 1), t);
        idxn = load_idx(index, min(tile + 3 * PGRID, NT - 1), t);

        bar_lgkm();                          // E2
        cur ^= 1;
    }
}

// ---------------------------------------------------------------------------
extern "C" void kernel_launch(void* const* d_in, const int* in_sizes, int n_in,
                              void* d_out, int out_size, void* d_ws, size_t ws_size,
                              hipStream_t stream)
{
    const float* x     = (const float*)d_in[0];
    const int*   index = (const int*)  d_in[1];
    const float* itp   = (const float*)d_in[2];
    const float* w     = (const float*)d_in[3];
    const float* bias  = (const float*)d_in[4];
    float*       out   = (float*)d_out;

    unsigned short* xt = (unsigned short*)d_ws;     // NV*128*2 B = 10.5 MB

    const int vtiles = (NV + VT - 1) / VT;   // 161
    hipLaunchKernelGGL(transpose_x_bf16, dim3(vtiles * NBS), dim3(256), 0,
                       stream, x, (unsigned*)xt);
    hipLaunchKernelGGL(sparse_conv_mfma, dim3(PGRID), dim3(512), 0,
                       stream, xt, index, itp, w, bias, out);
}